// Round 6
// baseline (1984.460 us; speedup 1.0000x reference)
//
#include <hip/hip_runtime.h>
#include <hip/hip_bf16.h>
#include <cstdint>

#define B_   32
#define CIN  12
#define L_   1024
#define T_   64
#define C1_  64
#define C2_  128
#define K_   7
#define PAD_ 3

typedef __attribute__((ext_vector_type(8))) short short8;
typedef __attribute__((ext_vector_type(4))) float float4v;

// ---- workspace layout (bytes) ----
// s1T : bf16 [B][L][half(2)][T][32]  = 268,435,456   (c1 split in two 32-halves)
// w2hi: bf16 A-frag-linear [k7][h2][mt8][lane64][j8] = 114,688
// w2lo: same                                         = 114,688
// accL: f32  [B][L][C2]              = 16,777,216
#define WS_S1T   0ull
#define WS_W2HI  268435456ull
#define WS_W2LO  (WS_W2HI + 114688ull)
#define WS_ACCL  (WS_W2LO + 114688ull)

// ---------------- K0: split w2 into bf16 hi/lo, A-fragment-linear layout ----------------
// Output index for (c2, c1, kk):  h=c1/32, kq=(c1%32)/8, j=c1%8, mt=c2/16, lane=kq*16+c2%16
// -> ((((kk*2+h)*8+mt)*64+lane)*8+j.  K2's A-load is then one contiguous 1KB dwordx4/wave.
__global__ __launch_bounds__(256) void k0_prep_w2(const float* __restrict__ w2,
                                                  ushort* __restrict__ w2hi,
                                                  ushort* __restrict__ w2lo) {
    int i = blockIdx.x * 256 + threadIdx.x;
    if (i >= C2_ * K_ * C1_) return;
    int c2 = i / (K_ * C1_);
    int r  = i % (K_ * C1_);
    int kk = r / C1_;
    int c1 = r % C1_;
    float w = w2[(c2 * C1_ + c1) * K_ + kk];
    __hip_bfloat16 hb = __float2bfloat16(w);
    float hf = __bfloat162float(hb);
    __hip_bfloat16 lb = __float2bfloat16(w - hf);
    ushort uh, ul;
    __builtin_memcpy(&uh, &hb, 2);
    __builtin_memcpy(&ul, &lb, 2);
    int h    = c1 >> 5;
    int kq   = (c1 >> 3) & 3;
    int j    = c1 & 7;
    int mt   = c2 >> 4;
    int lane = kq * 16 + (c2 & 15);
    int o    = ((((kk * 2 + h) * 8 + mt) * 64) + lane) * 8 + j;
    w2hi[o] = uh;
    w2lo[o] = ul;
}

// ---------------- K1: conv1 + LIF1 spike -> s1T bf16 [b][l][half][t][32] ----------------
// Threads (t=64, c1c=8): each owns 8 c1 x 8 l. Sliding x-window xw[14] per cin.
// launch_bounds(512,2): min_waves=4 made the allocator pick 64 VGPR and spill
// (R3: 6.9 GB HBM, 1722 us). min_waves=2 -> cap 256, ~100 needed, no spill.
__global__ __launch_bounds__(512, 2) void k1_conv1(const float* __restrict__ x,
                                                   const float* __restrict__ w1,
                                                   const float* __restrict__ b1,
                                                   ushort* __restrict__ s1t) {
    __shared__ ushort St[8 * 64 * 66];    // [row = j*64+t][c1 pad 66] = 67,584 B
    int t    = threadIdx.x;               // 0..63
    int c1c  = threadIdx.y;               // 0..7  (wave-uniform: wave = one c1c)
    int b    = blockIdx.y;
    int lbase = blockIdx.x * 8;

    float h[8][8];                        // [c1i][j]
    #pragma unroll
    for (int c1i = 0; c1i < 8; ++c1i) {
        float bias = b1[c1c * 8 + c1i];
        #pragma unroll
        for (int j = 0; j < 8; ++j) h[c1i][j] = bias;
    }

    #pragma unroll 2
    for (int cin = 0; cin < CIN; ++cin) {
        float xw[14];
        #pragma unroll
        for (int i = 0; i < 14; ++i) {
            int gl = lbase + i - PAD_;
            xw[i] = (gl >= 0 && gl < L_)
                ? x[(((size_t)b * CIN + cin) * L_ + gl) * T_ + t] : 0.0f;
        }
        #pragma unroll
        for (int dl = 0; dl < K_; ++dl)
            #pragma unroll
            for (int c1i = 0; c1i < 8; ++c1i) {
                float wv = w1[(c1c * 8 + c1i) * (CIN * K_) + cin * K_ + dl];
                #pragma unroll
                for (int j = 0; j < 8; ++j)
                    h[c1i][j] = fmaf(wv, xw[j + dl], h[c1i][j]);
            }
    }

    // spike -> LDS (packed ushort2 writes, row stride 33 dwords -> conflict-free)
    #pragma unroll
    for (int j = 0; j < 8; ++j)
        #pragma unroll
        for (int p = 0; p < 4; ++p) {
            uint s0 = (h[2 * p][j]     * 2.0f >= 0.5f) ? 0x3F80u : 0u;
            uint s1 = (h[2 * p + 1][j] * 2.0f >= 0.5f) ? 0x3F80u : 0u;
            *(uint*)&St[(j * 64 + t) * 66 + c1c * 8 + 2 * p] = s0 | (s1 << 16);
        }
    __syncthreads();

    // flush: 512 rows x 128 B, fully coalesced 16B granules; LDS 2-way (free)
    int i0 = c1c * 64 + t;                // 0..511
    #pragma unroll
    for (int rep = 0; rep < 8; ++rep) {
        int idx  = rep * 512 + i0;        // 0..4095
        int row  = idx >> 3;              // j*64 + t
        int gq   = idx & 7;               // granule: half = gq>>2, c1r8 = (gq&3)*8
        uint4 v  = *(const uint4*)&St[row * 66 + gq * 8];
        int j    = row >> 6, tt = row & 63;
        int half = gq >> 2,  c1r = (gq & 3) * 8;
        size_t off = ((((size_t)b * L_ + lbase + j) * 2 + half) * T_ + tt) * 32 + c1r;
        *(uint4*)&s1t[off] = v;
    }
}

// ---------------- K2: conv2 (bf16 MFMA hi/lo) + fused LIF2 + spike count ----------------
// 256 thr = 4 waves. Wave ng owns l = lb+ng, ALL 128 c2 (8 m-frags) x 64 t (4 n-frags).
// B staged in MFMA-fragment-linear LDS layout -> lane-linear conflict-free ds_read_b128.
// A loaded fragment-linear from global (1 KB coalesced/wave, cross-wave L1 reuse).
// kk loop is unroll-1: full h*kk*mt unroll let the scheduler hoist up to 224 A-loads
// -> peak reg pressure >> 256 -> 3.16 GB scratch writes (R5). Per-iter live set ~233.
__global__ __launch_bounds__(256, 2) void k2_conv2_lif(const ushort* __restrict__ s1t,
                                                       const ushort* __restrict__ w2hi,
                                                       const ushort* __restrict__ w2lo,
                                                       const float* __restrict__ b2,
                                                       float* __restrict__ accl) {
    __shared__ __align__(16) ushort S[2 * 20480];   // 81,920 B; [h][l'10][nt4][kq4][t15 16][j8]
    int tid    = threadIdx.x;
    int wv     = tid >> 6;         // 0..3 = l within tile
    int lane   = tid & 63;
    int b      = blockIdx.y;
    int lb     = blockIdx.x * 4;
    int lane15 = lane & 15;
    int kq     = lane >> 4;

    float4v acc[8][4];
    #pragma unroll
    for (int i = 0; i < 8; ++i)
        #pragma unroll
        for (int j = 0; j < 4; ++j)
            acc[i][j] = (float4v){0.0f, 0.0f, 0.0f, 0.0f};

    // ---- staging (rows (l',t) of 64 B, coalesced) ----
    #define STAGE(H)                                                                     \
        for (int it = 0; it < 3; ++it) {                                                 \
            int u = it * 256 + tid;                                                      \
            if (u < 640) {                                                               \
                int lp = u >> 6, t = u & 63;                                             \
                int gl = lb + lp - PAD_;                                                 \
                uint4 v0 = {0,0,0,0}, v1 = {0,0,0,0}, v2 = {0,0,0,0}, v3 = {0,0,0,0};    \
                if (gl >= 0 && gl < L_) {                                                \
                    const uint4* q = (const uint4*)&s1t[((((size_t)b * L_ + gl) * 2 + (H)) * T_ + t) * 32]; \
                    v0 = q[0]; v1 = q[1]; v2 = q[2]; v3 = q[3];                          \
                }                                                                        \
                int nt = t >> 4, t15 = t & 15;                                           \
                ushort* dst = &S[(H) * 20480];                                           \
                *(uint4*)&dst[(((lp * 4 + nt) * 4 + 0) * 16 + t15) * 8] = v0;            \
                *(uint4*)&dst[(((lp * 4 + nt) * 4 + 1) * 16 + t15) * 8] = v1;            \
                *(uint4*)&dst[(((lp * 4 + nt) * 4 + 2) * 16 + t15) * 8] = v2;            \
                *(uint4*)&dst[(((lp * 4 + nt) * 4 + 3) * 16 + t15) * 8] = v3;            \
            }                                                                            \
        }

    STAGE(0)
    __syncthreads();
    STAGE(1)                      // writes S[1]; S[0] being read is untouched

    #pragma unroll 1
    for (int h = 0; h < 2; ++h) {
        if (h == 1) __syncthreads();     // S[1] ready
        const ushort* Sh = &S[h * 20480];
        #pragma unroll 1
        for (int kk = 0; kk < K_; ++kk) {
            int lp = wv + kk;            // l' for this wave's output l
            short8 bf[4];
            #pragma unroll
            for (int nt = 0; nt < 4; ++nt)
                bf[nt] = *(const short8*)&Sh[(((lp * 4 + nt) * 4) * 16) * 8 + lane * 8];
            #pragma unroll
            for (int mt = 0; mt < 8; ++mt) {
                size_t aoff = ((((size_t)kk * 2 + h) * 8 + mt) * 64 + lane) * 8;
                short8 ahi = *(const short8*)&w2hi[aoff];
                short8 alo = *(const short8*)&w2lo[aoff];
                #pragma unroll
                for (int nt = 0; nt < 4; ++nt) {
                    acc[mt][nt] = __builtin_amdgcn_mfma_f32_16x16x32_bf16(ahi, bf[nt], acc[mt][nt], 0, 0, 0);
                    acc[mt][nt] = __builtin_amdgcn_mfma_f32_16x16x32_bf16(alo, bf[nt], acc[mt][nt], 0, 0, 0);
                }
            }
        }
    }
    __syncthreads();    // all S reads done before epilogue overwrites the region

    // ---- wave-private epilogue: transpose 64 c2 at a time, sequential LIF2 t-scan ----
    float* E = ((float*)S) + wv * (64 * 65);     // 16,640 B per wave, pad-65 rows
    int l = lb + wv;
    #pragma unroll 1
    for (int chunk = 0; chunk < 2; ++chunk) {
        #pragma unroll
        for (int mt4 = 0; mt4 < 4; ++mt4) {
            int mt = chunk * 4 + mt4;
            #pragma unroll
            for (int nt = 0; nt < 4; ++nt) {
                int t = nt * 16 + lane15;
                #pragma unroll
                for (int r = 0; r < 4; ++r)
                    E[t * 65 + mt4 * 16 + kq * 4 + r] = acc[mt][nt][r];
            }
        }
        __builtin_amdgcn_s_waitcnt(0);           // lgkmcnt(0): wave-local LDS RAW
        float bias = b2[chunk * 64 + lane];
        float v = 0.0f, cnt = 0.0f;
        #pragma unroll 8
        for (int t = 0; t < T_; ++t) {
            float hh = (E[t * 65 + lane] + bias) * 2.0f;
            v = v + (hh - v) / 0.9f;             // match ref arithmetic exactly
            bool sp = (v >= 0.5f);
            cnt += sp ? 1.0f : 0.0f;
            v = sp ? 0.0f : v;
        }
        accl[((size_t)b * L_ + l) * C2_ + chunk * 64 + lane] = cnt;
    }
}

// ---------------- K3: mean-pool over (t,l) + fc ----------------
__global__ __launch_bounds__(128) void k3_fc(const float* __restrict__ accl,
                                             const float* __restrict__ fcw,
                                             const float* __restrict__ fcb,
                                             float* __restrict__ out) {
    __shared__ float p[C2_];
    int b = blockIdx.x, c = threadIdx.x;
    float s = 0.0f;
    for (int l = 0; l < L_; ++l)
        s += accl[((size_t)b * L_ + l) * C2_ + c];
    p[c] = s * (1.0f / 65536.0f);     // / (T * L), exact pow2
    __syncthreads();
    if (c < 4) {
        float o = fcb[c];
        #pragma unroll 8
        for (int i = 0; i < C2_; ++i)
            o = fmaf(fcw[c * C2_ + i], p[i], o);
        out[b * 4 + c] = o;
    }
}

extern "C" void kernel_launch(void* const* d_in, const int* in_sizes, int n_in,
                              void* d_out, int out_size, void* d_ws, size_t ws_size,
                              hipStream_t stream) {
    const float* x   = (const float*)d_in[0];
    const float* w1  = (const float*)d_in[1];
    const float* b1  = (const float*)d_in[2];
    const float* w2  = (const float*)d_in[3];
    const float* b2  = (const float*)d_in[4];
    const float* fcw = (const float*)d_in[5];
    const float* fcb = (const float*)d_in[6];
    float* out = (float*)d_out;

    char* ws = (char*)d_ws;
    ushort* s1t  = (ushort*)(ws + WS_S1T);
    ushort* w2h  = (ushort*)(ws + WS_W2HI);
    ushort* w2l  = (ushort*)(ws + WS_W2LO);
    float*  accl = (float*)(ws + WS_ACCL);

    k0_prep_w2<<<dim3((C2_ * K_ * C1_ + 255) / 256), dim3(256), 0, stream>>>(w2, w2h, w2l);
    k1_conv1<<<dim3(L_ / 8, B_), dim3(64, 8), 0, stream>>>(x, w1, b1, s1t);
    k2_conv2_lif<<<dim3(L_ / 4, B_), dim3(256), 0, stream>>>(s1t, w2h, w2l, b2, accl);
    k3_fc<<<dim3(B_), dim3(128), 0, stream>>>(accl, fcw, fcb, out);
}

// Round 7
// 1640.088 us; speedup vs baseline: 1.2100x; 1.2100x over previous
//
#include <hip/hip_runtime.h>
#include <hip/hip_bf16.h>
#include <cstdint>

#define B_   32
#define CIN  12
#define L_   1024
#define T_   64
#define C1_  64
#define C2_  128
#define K_   7
#define PAD_ 3

typedef __attribute__((ext_vector_type(8))) short short8;
typedef __attribute__((ext_vector_type(4))) float float4v;

// ---- workspace layout (bytes) ----
// s1T : bf16 [B][L][half(2)][T][32]  = 268,435,456   (c1 split in two 32-halves)
// w2hi: bf16 A-frag-linear [k7][h2][mt8][lane64][j8] = 114,688
// w2lo: same                                         = 114,688
// accL: f32  [B][L][C2]              = 16,777,216
#define WS_S1T   0ull
#define WS_W2HI  268435456ull
#define WS_W2LO  (WS_W2HI + 114688ull)
#define WS_ACCL  (WS_W2LO + 114688ull)

// ---------------- K0: split w2 into bf16 hi/lo, A-fragment-linear layout ----------------
// Output index for (c2, c1, kk):  h=c1/32, kq=(c1%32)/8, j=c1%8, mt=c2/16, lane=kq*16+c2%16
// -> ((((kk*2+h)*8+mt)*64+lane)*8+j.  K2's A-load is then one contiguous 1KB dwordx4/wave.
__global__ __launch_bounds__(256) void k0_prep_w2(const float* __restrict__ w2,
                                                  ushort* __restrict__ w2hi,
                                                  ushort* __restrict__ w2lo) {
    int i = blockIdx.x * 256 + threadIdx.x;
    if (i >= C2_ * K_ * C1_) return;
    int c2 = i / (K_ * C1_);
    int r  = i % (K_ * C1_);
    int kk = r / C1_;
    int c1 = r % C1_;
    float w = w2[(c2 * C1_ + c1) * K_ + kk];
    __hip_bfloat16 hb = __float2bfloat16(w);
    float hf = __bfloat162float(hb);
    __hip_bfloat16 lb = __float2bfloat16(w - hf);
    ushort uh, ul;
    __builtin_memcpy(&uh, &hb, 2);
    __builtin_memcpy(&ul, &lb, 2);
    int h    = c1 >> 5;
    int kq   = (c1 >> 3) & 3;
    int j    = c1 & 7;
    int mt   = c2 >> 4;
    int lane = kq * 16 + (c2 & 15);
    int o    = ((((kk * 2 + h) * 8 + mt) * 64) + lane) * 8 + j;
    w2hi[o] = uh;
    w2lo[o] = ul;
}

// ---------------- K1: conv1 + LIF1 spike -> s1T bf16 [b][l][half][t][32] ----------------
// Threads (t=64, c1c=8): each owns 8 c1 x 8 l. Sliding x-window xw[14] per cin.
// launch_bounds(512,2): min_waves=4 made the allocator pick 64 VGPR and spill
// (R3: 6.9 GB HBM, 1722 us). min_waves=2 -> cap 256, ~100 needed, no spill.
__global__ __launch_bounds__(512, 2) void k1_conv1(const float* __restrict__ x,
                                                   const float* __restrict__ w1,
                                                   const float* __restrict__ b1,
                                                   ushort* __restrict__ s1t) {
    __shared__ ushort St[8 * 64 * 66];    // [row = j*64+t][c1 pad 66] = 67,584 B
    int t    = threadIdx.x;               // 0..63
    int c1c  = threadIdx.y;               // 0..7  (wave-uniform: wave = one c1c)
    int b    = blockIdx.y;
    int lbase = blockIdx.x * 8;

    float h[8][8];                        // [c1i][j]
    #pragma unroll
    for (int c1i = 0; c1i < 8; ++c1i) {
        float bias = b1[c1c * 8 + c1i];
        #pragma unroll
        for (int j = 0; j < 8; ++j) h[c1i][j] = bias;
    }

    #pragma unroll 2
    for (int cin = 0; cin < CIN; ++cin) {
        float xw[14];
        #pragma unroll
        for (int i = 0; i < 14; ++i) {
            int gl = lbase + i - PAD_;
            xw[i] = (gl >= 0 && gl < L_)
                ? x[(((size_t)b * CIN + cin) * L_ + gl) * T_ + t] : 0.0f;
        }
        #pragma unroll
        for (int dl = 0; dl < K_; ++dl)
            #pragma unroll
            for (int c1i = 0; c1i < 8; ++c1i) {
                float wv = w1[(c1c * 8 + c1i) * (CIN * K_) + cin * K_ + dl];
                #pragma unroll
                for (int j = 0; j < 8; ++j)
                    h[c1i][j] = fmaf(wv, xw[j + dl], h[c1i][j]);
            }
    }

    // spike -> LDS (packed ushort2 writes, row stride 33 dwords -> conflict-free)
    #pragma unroll
    for (int j = 0; j < 8; ++j)
        #pragma unroll
        for (int p = 0; p < 4; ++p) {
            uint s0 = (h[2 * p][j]     * 2.0f >= 0.5f) ? 0x3F80u : 0u;
            uint s1 = (h[2 * p + 1][j] * 2.0f >= 0.5f) ? 0x3F80u : 0u;
            *(uint*)&St[(j * 64 + t) * 66 + c1c * 8 + 2 * p] = s0 | (s1 << 16);
        }
    __syncthreads();

    // flush: 512 rows x 128 B, fully coalesced 16B granules; LDS 2-way (free)
    int i0 = c1c * 64 + t;                // 0..511
    #pragma unroll
    for (int rep = 0; rep < 8; ++rep) {
        int idx  = rep * 512 + i0;        // 0..4095
        int row  = idx >> 3;              // j*64 + t
        int gq   = idx & 7;               // granule: half = gq>>2, c1r8 = (gq&3)*8
        uint4 v  = *(const uint4*)&St[row * 66 + gq * 8];
        int j    = row >> 6, tt = row & 63;
        int half = gq >> 2,  c1r = (gq & 3) * 8;
        size_t off = ((((size_t)b * L_ + lbase + j) * 2 + half) * T_ + tt) * 32 + c1r;
        *(uint4*)&s1t[off] = v;
    }
}

// ---------------- K2: conv2 (bf16 MFMA hi/lo) + fused LIF2 + spike count ----------------
// R5/R6 post-mortem: wave-owns-128-c2 needed 128 acc + 16 in-flight A dwordx4 > 256-reg
// budget -> 3.16 GB structural scratch traffic regardless of unroll pragmas.
// New shape (m97-class): block = 128 c2 x 128 n (2 l x 64 t), 4 waves in 2x2 (m,n) grid.
// Wave: 64 c2 (4 m-frags) x 64 t at l = lb+wn -> 16 frags = 64 acc regs, A 8 short8/step.
// Live set ~170 regs -> no spill, ~3 blocks/CU. Single 32KB LDS stage per c1-half.
__global__ __launch_bounds__(256, 2) void k2_conv2_lif(const ushort* __restrict__ s1t,
                                                       const ushort* __restrict__ w2hi,
                                                       const ushort* __restrict__ w2lo,
                                                       const float* __restrict__ b2,
                                                       float* __restrict__ accl) {
    __shared__ __align__(16) unsigned char lds_raw[33792];
    ushort* S = (ushort*)lds_raw;   // stage: [l'8][nt4][kq4][t15 16][j8] = 32,768 B (one h)
    int tid    = threadIdx.x;
    int wv     = tid >> 6;
    int lane   = tid & 63;
    int wm     = wv >> 1;          // m half: c2 in [wm*64, wm*64+64)
    int wn     = wv & 1;           // n half: l = lb + wn
    int b      = blockIdx.y;
    int lb     = blockIdx.x * 2;
    int lane15 = lane & 15;
    int kq     = lane >> 4;

    float4v acc[4][4];             // [m-frag][n-frag], 64 regs
    #pragma unroll
    for (int i = 0; i < 4; ++i)
        #pragma unroll
        for (int j = 0; j < 4; ++j)
            acc[i][j] = (float4v){0.0f, 0.0f, 0.0f, 0.0f};

    #pragma unroll 1
    for (int h = 0; h < 2; ++h) {
        __syncthreads();           // S reads of previous h done
        // stage S = s1T[b][lb-3 .. lb+4][h][t][0..31]; rows of 64 B, thread owns one row's 4 uint4
        #pragma unroll
        for (int it = 0; it < 2; ++it) {
            int u  = it * 256 + tid;     // 0..511 = (l' 8) x (t 64)
            int lp = u >> 6, t = u & 63;
            int gl = lb + lp - PAD_;
            uint4 v0 = {0,0,0,0}, v1 = {0,0,0,0}, v2 = {0,0,0,0}, v3 = {0,0,0,0};
            if (gl >= 0 && gl < L_) {
                const uint4* q = (const uint4*)&s1t[((((size_t)b * L_ + gl) * 2 + h) * T_ + t) * 32];
                v0 = q[0]; v1 = q[1]; v2 = q[2]; v3 = q[3];
            }
            int nt = t >> 4, t15 = t & 15;
            *(uint4*)&S[(((lp * 4 + nt) * 4 + 0) * 16 + t15) * 8] = v0;
            *(uint4*)&S[(((lp * 4 + nt) * 4 + 1) * 16 + t15) * 8] = v1;
            *(uint4*)&S[(((lp * 4 + nt) * 4 + 2) * 16 + t15) * 8] = v2;
            *(uint4*)&S[(((lp * 4 + nt) * 4 + 3) * 16 + t15) * 8] = v3;
        }
        __syncthreads();
        #pragma unroll 1
        for (int kk = 0; kk < K_; ++kk) {
            int lp = wn + kk;            // staged row feeding output l = lb+wn at tap kk
            short8 bf[4];
            #pragma unroll
            for (int nt = 0; nt < 4; ++nt)   // lane-linear 2KB frag -> conflict-free b128
                bf[nt] = *(const short8*)&S[(((lp * 4 + nt) * 4) * 16) * 8 + lane * 8];
            #pragma unroll
            for (int mf = 0; mf < 4; ++mf) {
                size_t aoff = ((((size_t)kk * 2 + h) * 8 + wm * 4 + mf) * 64 + lane) * 8;
                short8 ahi = *(const short8*)&w2hi[aoff];
                short8 alo = *(const short8*)&w2lo[aoff];
                #pragma unroll
                for (int nt = 0; nt < 4; ++nt) {
                    acc[mf][nt] = __builtin_amdgcn_mfma_f32_16x16x32_bf16(ahi, bf[nt], acc[mf][nt], 0, 0, 0);
                    acc[mf][nt] = __builtin_amdgcn_mfma_f32_16x16x32_bf16(alo, bf[nt], acc[mf][nt], 0, 0, 0);
                }
            }
        }
    }
    __syncthreads();    // all S reads done before epilogue reuses the region

    // ---- wave-private epilogue: 2 chunks of 32 c2 -> LDS transpose -> LIF2 t-scan ----
    float* E = ((float*)lds_raw) + wv * (64 * 33);    // 8448 B per wave
    int l = lb + wn;
    #pragma unroll 1
    for (int chunk = 0; chunk < 2; ++chunk) {
        #pragma unroll
        for (int mfl = 0; mfl < 2; ++mfl) {
            int mf = chunk * 2 + mfl;
            #pragma unroll
            for (int nt = 0; nt < 4; ++nt) {
                int t = nt * 16 + lane15;             // D: col = lane&15
                #pragma unroll
                for (int r = 0; r < 4; ++r)
                    E[t * 33 + mfl * 16 + kq * 4 + r] = acc[mf][nt][r];   // D: row = quad*4+reg
            }
        }
        __builtin_amdgcn_s_waitcnt(0);                // lgkmcnt(0): wave-local LDS RAW
        if (lane < 32) {
            int c2 = wm * 64 + chunk * 32 + lane;
            float bias = b2[c2];
            float v = 0.0f, cnt = 0.0f;
            #pragma unroll 8
            for (int t = 0; t < T_; ++t) {
                float hh = (E[t * 33 + lane] + bias) * 2.0f;
                v = v + (hh - v) / 0.9f;              // match ref arithmetic exactly
                bool sp = (v >= 0.5f);
                cnt += sp ? 1.0f : 0.0f;
                v = sp ? 0.0f : v;
            }
            accl[((size_t)b * L_ + l) * C2_ + c2] = cnt;
        }
        __builtin_amdgcn_s_waitcnt(0);                // reads done before next chunk overwrites
    }
}

// ---------------- K3: mean-pool over (t,l) + fc ----------------
__global__ __launch_bounds__(128) void k3_fc(const float* __restrict__ accl,
                                             const float* __restrict__ fcw,
                                             const float* __restrict__ fcb,
                                             float* __restrict__ out) {
    __shared__ float p[C2_];
    int b = blockIdx.x, c = threadIdx.x;
    float s = 0.0f;
    for (int l = 0; l < L_; ++l)
        s += accl[((size_t)b * L_ + l) * C2_ + c];
    p[c] = s * (1.0f / 65536.0f);     // / (T * L), exact pow2
    __syncthreads();
    if (c < 4) {
        float o = fcb[c];
        #pragma unroll 8
        for (int i = 0; i < C2_; ++i)
            o = fmaf(fcw[c * C2_ + i], p[i], o);
        out[b * 4 + c] = o;
    }
}

extern "C" void kernel_launch(void* const* d_in, const int* in_sizes, int n_in,
                              void* d_out, int out_size, void* d_ws, size_t ws_size,
                              hipStream_t stream) {
    const float* x   = (const float*)d_in[0];
    const float* w1  = (const float*)d_in[1];
    const float* b1  = (const float*)d_in[2];
    const float* w2  = (const float*)d_in[3];
    const float* b2  = (const float*)d_in[4];
    const float* fcw = (const float*)d_in[5];
    const float* fcb = (const float*)d_in[6];
    float* out = (float*)d_out;

    char* ws = (char*)d_ws;
    ushort* s1t  = (ushort*)(ws + WS_S1T);
    ushort* w2h  = (ushort*)(ws + WS_W2HI);
    ushort* w2l  = (ushort*)(ws + WS_W2LO);
    float*  accl = (float*)(ws + WS_ACCL);

    k0_prep_w2<<<dim3((C2_ * K_ * C1_ + 255) / 256), dim3(256), 0, stream>>>(w2, w2h, w2l);
    k1_conv1<<<dim3(L_ / 8, B_), dim3(64, 8), 0, stream>>>(x, w1, b1, s1t);
    k2_conv2_lif<<<dim3(L_ / 2, B_), dim3(256), 0, stream>>>(s1t, w2h, w2l, b2, accl);
    k3_fc<<<dim3(B_), dim3(128), 0, stream>>>(accl, fcw, fcb, out);
}

// Round 8
// 1223.003 us; speedup vs baseline: 1.6226x; 1.3410x over previous
//
#include <hip/hip_runtime.h>
#include <hip/hip_bf16.h>
#include <cstdint>

#define B_   32
#define CIN  12
#define L_   1024
#define T_   64
#define C1_  64
#define C2_  128
#define K_   7
#define PAD_ 3

typedef __attribute__((ext_vector_type(8))) short short8;
typedef __attribute__((ext_vector_type(4))) float float4v;

// ---- workspace layout (bytes) ----
// s1T : bf16 [B][L][half(2)][T][32]  = 268,435,456   (c1 split in two 32-halves)
// w2hi: bf16 A-frag-linear [k7][h2][mt8][lane64][j8] = 114,688
// w2lo: same                                         = 114,688
// accL: f32  [B][L][C2]              = 16,777,216
#define WS_S1T   0ull
#define WS_W2HI  268435456ull
#define WS_W2LO  (WS_W2HI + 114688ull)
#define WS_ACCL  (WS_W2LO + 114688ull)

// ---------------- K0: split w2 into bf16 hi/lo, A-fragment-linear layout ----------------
// Output index for (c2, c1, kk):  h=c1/32, kq=(c1%32)/8, j=c1%8, mt=c2/16, lane=kq*16+c2%16
// -> ((((kk*2+h)*8+mt)*64+lane)*8+j.  K2's A-load is then one contiguous 1KB dwordx4/wave.
__global__ __launch_bounds__(256) void k0_prep_w2(const float* __restrict__ w2,
                                                  ushort* __restrict__ w2hi,
                                                  ushort* __restrict__ w2lo) {
    int i = blockIdx.x * 256 + threadIdx.x;
    if (i >= C2_ * K_ * C1_) return;
    int c2 = i / (K_ * C1_);
    int r  = i % (K_ * C1_);
    int kk = r / C1_;
    int c1 = r % C1_;
    float w = w2[(c2 * C1_ + c1) * K_ + kk];
    __hip_bfloat16 hb = __float2bfloat16(w);
    float hf = __bfloat162float(hb);
    __hip_bfloat16 lb = __float2bfloat16(w - hf);
    ushort uh, ul;
    __builtin_memcpy(&uh, &hb, 2);
    __builtin_memcpy(&ul, &lb, 2);
    int h    = c1 >> 5;
    int kq   = (c1 >> 3) & 3;
    int j    = c1 & 7;
    int mt   = c2 >> 4;
    int lane = kq * 16 + (c2 & 15);
    int o    = ((((kk * 2 + h) * 8 + mt) * 64) + lane) * 8 + j;
    w2hi[o] = uh;
    w2lo[o] = ul;
}

// ---------------- K1: conv1 + LIF1 spike -> s1T bf16 [b][l][half][t][32] ----------------
// Threads (t=64, c1c=8): each owns 8 c1 x 8 l. Sliding x-window xw[14] per cin.
// launch_bounds(512,2): min_waves=4 made the allocator pick 64 VGPR and spill
// (R3: 6.9 GB HBM, 1722 us). min_waves=2 -> cap 256, ~100 needed, no spill.
__global__ __launch_bounds__(512, 2) void k1_conv1(const float* __restrict__ x,
                                                   const float* __restrict__ w1,
                                                   const float* __restrict__ b1,
                                                   ushort* __restrict__ s1t) {
    __shared__ ushort St[8 * 64 * 66];    // [row = j*64+t][c1 pad 66] = 67,584 B
    int t    = threadIdx.x;               // 0..63
    int c1c  = threadIdx.y;               // 0..7  (wave-uniform: wave = one c1c)
    int b    = blockIdx.y;
    int lbase = blockIdx.x * 8;

    float h[8][8];                        // [c1i][j]
    #pragma unroll
    for (int c1i = 0; c1i < 8; ++c1i) {
        float bias = b1[c1c * 8 + c1i];
        #pragma unroll
        for (int j = 0; j < 8; ++j) h[c1i][j] = bias;
    }

    #pragma unroll 2
    for (int cin = 0; cin < CIN; ++cin) {
        float xw[14];
        #pragma unroll
        for (int i = 0; i < 14; ++i) {
            int gl = lbase + i - PAD_;
            xw[i] = (gl >= 0 && gl < L_)
                ? x[(((size_t)b * CIN + cin) * L_ + gl) * T_ + t] : 0.0f;
        }
        #pragma unroll
        for (int dl = 0; dl < K_; ++dl)
            #pragma unroll
            for (int c1i = 0; c1i < 8; ++c1i) {
                float wv = w1[(c1c * 8 + c1i) * (CIN * K_) + cin * K_ + dl];
                #pragma unroll
                for (int j = 0; j < 8; ++j)
                    h[c1i][j] = fmaf(wv, xw[j + dl], h[c1i][j]);
            }
    }

    // spike -> LDS (packed ushort2 writes, row stride 33 dwords -> conflict-free)
    #pragma unroll
    for (int j = 0; j < 8; ++j)
        #pragma unroll
        for (int p = 0; p < 4; ++p) {
            uint s0 = (h[2 * p][j]     * 2.0f >= 0.5f) ? 0x3F80u : 0u;
            uint s1 = (h[2 * p + 1][j] * 2.0f >= 0.5f) ? 0x3F80u : 0u;
            *(uint*)&St[(j * 64 + t) * 66 + c1c * 8 + 2 * p] = s0 | (s1 << 16);
        }
    __syncthreads();

    // flush: 512 rows x 128 B, fully coalesced 16B granules; LDS 2-way (free)
    int i0 = c1c * 64 + t;                // 0..511
    #pragma unroll
    for (int rep = 0; rep < 8; ++rep) {
        int idx  = rep * 512 + i0;        // 0..4095
        int row  = idx >> 3;              // j*64 + t
        int gq   = idx & 7;               // granule: half = gq>>2, c1r8 = (gq&3)*8
        uint4 v  = *(const uint4*)&St[row * 66 + gq * 8];
        int j    = row >> 6, tt = row & 63;
        int half = gq >> 2,  c1r = (gq & 3) * 8;
        size_t off = ((((size_t)b * L_ + lbase + j) * 2 + half) * T_ + tt) * 32 + c1r;
        *(uint4*)&s1t[off] = v;
    }
}

// ---------------- K2: conv2 (bf16 MFMA hi/lo) + fused LIF2 + spike count ----------------
// Block = 128 c2 x 128 n (2 l x 64 t), 4 waves in 2x2 (m,n) grid; wave = 64 c2 x 64 t.
// ROOT CAUSE of R5-R7's constant 3.16 GB WRITE_SIZE: the epilogue's `#pragma unroll 1`
// chunk loop indexed acc[chunk*2+mfl] dynamically -> whole acc array demoted to scratch
// for the kernel's lifetime. ALL acc indices must be compile-time constants: every loop
// that indexes acc is fully unrolled.
__global__ __launch_bounds__(256, 2) void k2_conv2_lif(const ushort* __restrict__ s1t,
                                                       const ushort* __restrict__ w2hi,
                                                       const ushort* __restrict__ w2lo,
                                                       const float* __restrict__ b2,
                                                       float* __restrict__ accl) {
    __shared__ __align__(16) unsigned char lds_raw[33792];
    ushort* S = (ushort*)lds_raw;   // stage: [l'8][nt4][kq4][t15 16][j8] = 32,768 B (one h)
    int tid    = threadIdx.x;
    int wv     = tid >> 6;
    int lane   = tid & 63;
    int wm     = wv >> 1;          // m half: c2 in [wm*64, wm*64+64)
    int wn     = wv & 1;           // n half: l = lb + wn
    int b      = blockIdx.y;
    int lb     = blockIdx.x * 2;
    int lane15 = lane & 15;
    int kq     = lane >> 4;

    float4v acc[4][4];             // [m-frag][n-frag], 64 regs — constant indices ONLY
    #pragma unroll
    for (int i = 0; i < 4; ++i)
        #pragma unroll
        for (int j = 0; j < 4; ++j)
            acc[i][j] = (float4v){0.0f, 0.0f, 0.0f, 0.0f};

    #pragma unroll 1
    for (int h = 0; h < 2; ++h) {
        __syncthreads();           // S reads of previous h done
        // stage S = s1T[b][lb-3 .. lb+4][h][t][0..31]; rows of 64 B, thread owns one row's 4 uint4
        #pragma unroll
        for (int it = 0; it < 2; ++it) {
            int u  = it * 256 + tid;     // 0..511 = (l' 8) x (t 64)
            int lp = u >> 6, t = u & 63;
            int gl = lb + lp - PAD_;
            uint4 v0 = {0,0,0,0}, v1 = {0,0,0,0}, v2 = {0,0,0,0}, v3 = {0,0,0,0};
            if (gl >= 0 && gl < L_) {
                const uint4* q = (const uint4*)&s1t[((((size_t)b * L_ + gl) * 2 + h) * T_ + t) * 32];
                v0 = q[0]; v1 = q[1]; v2 = q[2]; v3 = q[3];
            }
            int nt = t >> 4, t15 = t & 15;
            *(uint4*)&S[(((lp * 4 + nt) * 4 + 0) * 16 + t15) * 8] = v0;
            *(uint4*)&S[(((lp * 4 + nt) * 4 + 1) * 16 + t15) * 8] = v1;
            *(uint4*)&S[(((lp * 4 + nt) * 4 + 2) * 16 + t15) * 8] = v2;
            *(uint4*)&S[(((lp * 4 + nt) * 4 + 3) * 16 + t15) * 8] = v3;
        }
        __syncthreads();
        #pragma unroll 1
        for (int kk = 0; kk < K_; ++kk) {
            int lp = wn + kk;            // staged row feeding output l = lb+wn at tap kk
            short8 bf[4];
            #pragma unroll
            for (int nt = 0; nt < 4; ++nt)   // lane-linear 2KB frag -> conflict-free b128
                bf[nt] = *(const short8*)&S[(((lp * 4 + nt) * 4) * 16) * 8 + lane * 8];
            #pragma unroll
            for (int mf = 0; mf < 4; ++mf) {
                size_t aoff = ((((size_t)kk * 2 + h) * 8 + wm * 4 + mf) * 64 + lane) * 8;
                short8 ahi = *(const short8*)&w2hi[aoff];
                short8 alo = *(const short8*)&w2lo[aoff];
                #pragma unroll
                for (int nt = 0; nt < 4; ++nt) {
                    acc[mf][nt] = __builtin_amdgcn_mfma_f32_16x16x32_bf16(ahi, bf[nt], acc[mf][nt], 0, 0, 0);
                    acc[mf][nt] = __builtin_amdgcn_mfma_f32_16x16x32_bf16(alo, bf[nt], acc[mf][nt], 0, 0, 0);
                }
            }
        }
    }
    __syncthreads();    // all S reads done before epilogue reuses the region

    // ---- wave-private epilogue: 2 chunks of 32 c2 -> LDS transpose -> LIF2 t-scan ----
    // chunk loop FULLY unrolled so acc[chunk*2+mfl] is a constant index (see header note).
    float* E = ((float*)lds_raw) + wv * (64 * 33);    // 8448 B per wave
    int l = lb + wn;
    #pragma unroll
    for (int chunk = 0; chunk < 2; ++chunk) {
        #pragma unroll
        for (int mfl = 0; mfl < 2; ++mfl) {
            int mf = chunk * 2 + mfl;
            #pragma unroll
            for (int nt = 0; nt < 4; ++nt) {
                int t = nt * 16 + lane15;             // D: col = lane&15
                #pragma unroll
                for (int r = 0; r < 4; ++r)
                    E[t * 33 + mfl * 16 + kq * 4 + r] = acc[mf][nt][r];   // D: row = quad*4+reg
            }
        }
        __builtin_amdgcn_s_waitcnt(0);                // lgkmcnt(0): wave-local LDS RAW
        if (lane < 32) {
            int c2 = wm * 64 + chunk * 32 + lane;
            float bias = b2[c2];
            float v = 0.0f, cnt = 0.0f;
            #pragma unroll 8
            for (int t = 0; t < T_; ++t) {
                float hh = (E[t * 33 + lane] + bias) * 2.0f;
                v = v + (hh - v) / 0.9f;              // match ref arithmetic exactly
                bool sp = (v >= 0.5f);
                cnt += sp ? 1.0f : 0.0f;
                v = sp ? 0.0f : v;
            }
            accl[((size_t)b * L_ + l) * C2_ + c2] = cnt;
        }
        __builtin_amdgcn_s_waitcnt(0);                // reads done before next chunk overwrites
    }
}

// ---------------- K3: mean-pool over (t,l) + fc ----------------
__global__ __launch_bounds__(128) void k3_fc(const float* __restrict__ accl,
                                             const float* __restrict__ fcw,
                                             const float* __restrict__ fcb,
                                             float* __restrict__ out) {
    __shared__ float p[C2_];
    int b = blockIdx.x, c = threadIdx.x;
    float s = 0.0f;
    for (int l = 0; l < L_; ++l)
        s += accl[((size_t)b * L_ + l) * C2_ + c];
    p[c] = s * (1.0f / 65536.0f);     // / (T * L), exact pow2
    __syncthreads();
    if (c < 4) {
        float o = fcb[c];
        #pragma unroll 8
        for (int i = 0; i < C2_; ++i)
            o = fmaf(fcw[c * C2_ + i], p[i], o);
        out[b * 4 + c] = o;
    }
}

extern "C" void kernel_launch(void* const* d_in, const int* in_sizes, int n_in,
                              void* d_out, int out_size, void* d_ws, size_t ws_size,
                              hipStream_t stream) {
    const float* x   = (const float*)d_in[0];
    const float* w1  = (const float*)d_in[1];
    const float* b1  = (const float*)d_in[2];
    const float* w2  = (const float*)d_in[3];
    const float* b2  = (const float*)d_in[4];
    const float* fcw = (const float*)d_in[5];
    const float* fcb = (const float*)d_in[6];
    float* out = (float*)d_out;

    char* ws = (char*)d_ws;
    ushort* s1t  = (ushort*)(ws + WS_S1T);
    ushort* w2h  = (ushort*)(ws + WS_W2HI);
    ushort* w2l  = (ushort*)(ws + WS_W2LO);
    float*  accl = (float*)(ws + WS_ACCL);

    k0_prep_w2<<<dim3((C2_ * K_ * C1_ + 255) / 256), dim3(256), 0, stream>>>(w2, w2h, w2l);
    k1_conv1<<<dim3(L_ / 8, B_), dim3(64, 8), 0, stream>>>(x, w1, b1, s1t);
    k2_conv2_lif<<<dim3(L_ / 2, B_), dim3(256), 0, stream>>>(s1t, w2h, w2l, b2, accl);
    k3_fc<<<dim3(B_), dim3(128), 0, stream>>>(accl, fcw, fcb, out);
}

// Round 9
// 831.970 us; speedup vs baseline: 2.3853x; 1.4700x over previous
//
#include <hip/hip_runtime.h>
#include <hip/hip_bf16.h>
#include <cstdint>

#define B_   32
#define CIN  12
#define L_   1024
#define T_   64
#define C1_  64
#define C2_  128
#define K_   7
#define PAD_ 3

typedef __attribute__((ext_vector_type(8))) short short8;
typedef __attribute__((ext_vector_type(4))) float float4v;

// ---- workspace layout (bytes) ----
// s1T : bf16 [B][L][half(2)][T][32]  = 268,435,456   (c1 split in two 32-halves)
// w2hi: bf16 A-frag-linear [k7][h2][mt8][lane64][j8] = 114,688
// accL: f32  [B][L][C2]              = 16,777,216
#define WS_S1T   0ull
#define WS_W2HI  268435456ull
#define WS_ACCL  (WS_W2HI + 2ull * 114688ull)   // keep legacy offset (lo slot unused)

// ---------------- K0: w2 -> bf16, A-fragment-linear layout ----------------
// Single-bf16 w2 (hi/lo correction dropped in R9): spike-flip error analysis gives
// out absmax ~5e-4 << 1.28e-2 threshold; halves K2's MFMA + A-load work.
// Index for (c2, c1, kk): h=c1/32, kq=(c1%32)/8, j=c1%8, mt=c2/16, lane=kq*16+c2%16
// -> ((((kk*2+h)*8+mt)*64+lane)*8+j.  K2's A-load is one contiguous 1KB dwordx4/wave.
__global__ __launch_bounds__(256) void k0_prep_w2(const float* __restrict__ w2,
                                                  ushort* __restrict__ w2hi) {
    int i = blockIdx.x * 256 + threadIdx.x;
    if (i >= C2_ * K_ * C1_) return;
    int c2 = i / (K_ * C1_);
    int r  = i % (K_ * C1_);
    int kk = r / C1_;
    int c1 = r % C1_;
    float w = w2[(c2 * C1_ + c1) * K_ + kk];
    __hip_bfloat16 hb = __float2bfloat16(w);
    ushort uh;
    __builtin_memcpy(&uh, &hb, 2);
    int h    = c1 >> 5;
    int kq   = (c1 >> 3) & 3;
    int j    = c1 & 7;
    int mt   = c2 >> 4;
    int lane = kq * 16 + (c2 & 15);
    int o    = ((((kk * 2 + h) * 8 + mt) * 64) + lane) * 8 + j;
    w2hi[o] = uh;
}

// ---------------- K1: conv1 + LIF1 spike -> s1T bf16 [b][l][half][t][32] ----------------
// Threads (t=64, c1c=8): each owns 8 c1 x 8 l. Sliding x-window xw[14] per cin.
// launch_bounds(512,2): min_waves=4 made the allocator pick 64 VGPR and spill
// (R3: 6.9 GB HBM, 1722 us). min_waves=2 -> cap 256, ~100 needed, no spill.
__global__ __launch_bounds__(512, 2) void k1_conv1(const float* __restrict__ x,
                                                   const float* __restrict__ w1,
                                                   const float* __restrict__ b1,
                                                   ushort* __restrict__ s1t) {
    __shared__ ushort St[8 * 64 * 66];    // [row = j*64+t][c1 pad 66] = 67,584 B
    int t    = threadIdx.x;               // 0..63
    int c1c  = threadIdx.y;               // 0..7  (wave-uniform: wave = one c1c)
    int b    = blockIdx.y;
    int lbase = blockIdx.x * 8;

    float h[8][8];                        // [c1i][j]
    #pragma unroll
    for (int c1i = 0; c1i < 8; ++c1i) {
        float bias = b1[c1c * 8 + c1i];
        #pragma unroll
        for (int j = 0; j < 8; ++j) h[c1i][j] = bias;
    }

    #pragma unroll 2
    for (int cin = 0; cin < CIN; ++cin) {
        float xw[14];
        #pragma unroll
        for (int i = 0; i < 14; ++i) {
            int gl = lbase + i - PAD_;
            xw[i] = (gl >= 0 && gl < L_)
                ? x[(((size_t)b * CIN + cin) * L_ + gl) * T_ + t] : 0.0f;
        }
        #pragma unroll
        for (int dl = 0; dl < K_; ++dl)
            #pragma unroll
            for (int c1i = 0; c1i < 8; ++c1i) {
                float wv = w1[(c1c * 8 + c1i) * (CIN * K_) + cin * K_ + dl];
                #pragma unroll
                for (int j = 0; j < 8; ++j)
                    h[c1i][j] = fmaf(wv, xw[j + dl], h[c1i][j]);
            }
    }

    // spike -> LDS (packed ushort2 writes, row stride 33 dwords -> conflict-free)
    #pragma unroll
    for (int j = 0; j < 8; ++j)
        #pragma unroll
        for (int p = 0; p < 4; ++p) {
            uint s0 = (h[2 * p][j]     * 2.0f >= 0.5f) ? 0x3F80u : 0u;
            uint s1 = (h[2 * p + 1][j] * 2.0f >= 0.5f) ? 0x3F80u : 0u;
            *(uint*)&St[(j * 64 + t) * 66 + c1c * 8 + 2 * p] = s0 | (s1 << 16);
        }
    __syncthreads();

    // flush: 512 rows x 128 B, fully coalesced 16B granules; LDS 2-way (free)
    int i0 = c1c * 64 + t;                // 0..511
    #pragma unroll
    for (int rep = 0; rep < 8; ++rep) {
        int idx  = rep * 512 + i0;        // 0..4095
        int row  = idx >> 3;              // j*64 + t
        int gq   = idx & 7;               // granule: half = gq>>2, c1r8 = (gq&3)*8
        uint4 v  = *(const uint4*)&St[row * 66 + gq * 8];
        int j    = row >> 6, tt = row & 63;
        int half = gq >> 2,  c1r = (gq & 3) * 8;
        size_t off = ((((size_t)b * L_ + lbase + j) * 2 + half) * T_ + tt) * 32 + c1r;
        *(uint4*)&s1t[off] = v;
    }
}

// ---------------- K2: conv2 (bf16 MFMA) + fused LIF2 + spike count ----------------
// Block = 128 c2 x 128 n (2 l x 64 t), 4 waves in 2x2 (m,n) grid; wave = 64 c2 x 64 t.
// INVARIANT (R5-R8 root cause): acc[][] must ONLY be indexed with compile-time
// constants; a dynamic index demotes the whole array to scratch for the kernel's
// lifetime (3.16 GB WRITE_SIZE). Every loop touching acc is fully unrolled.
__global__ __launch_bounds__(256, 2) void k2_conv2_lif(const ushort* __restrict__ s1t,
                                                       const ushort* __restrict__ w2hi,
                                                       const float* __restrict__ b2,
                                                       float* __restrict__ accl) {
    __shared__ __align__(16) unsigned char lds_raw[33792];
    ushort* S = (ushort*)lds_raw;   // stage: [l'8][nt4][kq4][t15 16][j8] = 32,768 B (one h)
    int tid    = threadIdx.x;
    int wv     = tid >> 6;
    int lane   = tid & 63;
    int wm     = wv >> 1;          // m half: c2 in [wm*64, wm*64+64)
    int wn     = wv & 1;           // n half: l = lb + wn
    int b      = blockIdx.y;
    int lb     = blockIdx.x * 2;
    int lane15 = lane & 15;
    int kq     = lane >> 4;

    float4v acc[4][4];             // [m-frag][n-frag], 64 regs — constant indices ONLY
    #pragma unroll
    for (int i = 0; i < 4; ++i)
        #pragma unroll
        for (int j = 0; j < 4; ++j)
            acc[i][j] = (float4v){0.0f, 0.0f, 0.0f, 0.0f};

    #pragma unroll 1
    for (int h = 0; h < 2; ++h) {
        __syncthreads();           // S reads of previous h done
        // stage S = s1T[b][lb-3 .. lb+4][h][t][0..31]; rows of 64 B, thread owns one row's 4 uint4
        #pragma unroll
        for (int it = 0; it < 2; ++it) {
            int u  = it * 256 + tid;     // 0..511 = (l' 8) x (t 64)
            int lp = u >> 6, t = u & 63;
            int gl = lb + lp - PAD_;
            uint4 v0 = {0,0,0,0}, v1 = {0,0,0,0}, v2 = {0,0,0,0}, v3 = {0,0,0,0};
            if (gl >= 0 && gl < L_) {
                const uint4* q = (const uint4*)&s1t[((((size_t)b * L_ + gl) * 2 + h) * T_ + t) * 32];
                v0 = q[0]; v1 = q[1]; v2 = q[2]; v3 = q[3];
            }
            int nt = t >> 4, t15 = t & 15;
            *(uint4*)&S[(((lp * 4 + nt) * 4 + 0) * 16 + t15) * 8] = v0;
            *(uint4*)&S[(((lp * 4 + nt) * 4 + 1) * 16 + t15) * 8] = v1;
            *(uint4*)&S[(((lp * 4 + nt) * 4 + 2) * 16 + t15) * 8] = v2;
            *(uint4*)&S[(((lp * 4 + nt) * 4 + 3) * 16 + t15) * 8] = v3;
        }
        __syncthreads();
        #pragma unroll 2
        for (int kk = 0; kk < K_; ++kk) {
            int lp = wn + kk;            // staged row feeding output l = lb+wn at tap kk
            short8 bf[4];
            #pragma unroll
            for (int nt = 0; nt < 4; ++nt)   // lane-linear 2KB frag -> conflict-free b128
                bf[nt] = *(const short8*)&S[(((lp * 4 + nt) * 4) * 16) * 8 + lane * 8];
            #pragma unroll
            for (int mf = 0; mf < 4; ++mf) {
                size_t aoff = ((((size_t)kk * 2 + h) * 8 + wm * 4 + mf) * 64 + lane) * 8;
                short8 ahi = *(const short8*)&w2hi[aoff];
                #pragma unroll
                for (int nt = 0; nt < 4; ++nt)
                    acc[mf][nt] = __builtin_amdgcn_mfma_f32_16x16x32_bf16(ahi, bf[nt], acc[mf][nt], 0, 0, 0);
            }
        }
    }
    __syncthreads();    // all S reads done before epilogue reuses the region

    // ---- wave-private epilogue: 2 chunks of 32 c2 -> LDS transpose -> LIF2 t-scan ----
    // chunk loop FULLY unrolled (acc constant-index invariant).
    // Scan arithmetic folded: v' = A*v + (E*Cs + D), A = 1-1/0.9, Cs = 2/0.9, D = bias*2/0.9.
    // Not bit-identical to ref (ulp-level) — flip-error analysis bounds out absmax ~1e-3.
    float* E = ((float*)lds_raw) + wv * (64 * 33);    // 8448 B per wave
    int l = lb + wn;
    const float Af = 1.0f - 1.0f / 0.9f;
    const float Cs = 2.0f / 0.9f;
    #pragma unroll
    for (int chunk = 0; chunk < 2; ++chunk) {
        #pragma unroll
        for (int mfl = 0; mfl < 2; ++mfl) {
            int mf = chunk * 2 + mfl;
            #pragma unroll
            for (int nt = 0; nt < 4; ++nt) {
                int t = nt * 16 + lane15;             // D: col = lane&15
                #pragma unroll
                for (int r = 0; r < 4; ++r)
                    E[t * 33 + mfl * 16 + kq * 4 + r] = acc[mf][nt][r];   // D: row = quad*4+reg
            }
        }
        __builtin_amdgcn_s_waitcnt(0);                // lgkmcnt(0): wave-local LDS RAW
        if (lane < 32) {
            int c2 = wm * 64 + chunk * 32 + lane;
            float D = b2[c2] * Cs;
            float v = 0.0f;
            uint cnt = 0u;
            #pragma unroll 8
            for (int t = 0; t < T_; ++t) {
                float e = fmaf(E[t * 33 + lane], Cs, D);
                v = fmaf(Af, v, e);
                bool sp = (v >= 0.5f);
                cnt += sp ? 1u : 0u;
                v = sp ? 0.0f : v;
            }
            accl[((size_t)b * L_ + l) * C2_ + c2] = (float)cnt;
        }
        __builtin_amdgcn_s_waitcnt(0);                // reads done before next chunk overwrites
    }
}

// ---------------- K3: mean-pool over (t,l) + fc ----------------
__global__ __launch_bounds__(128) void k3_fc(const float* __restrict__ accl,
                                             const float* __restrict__ fcw,
                                             const float* __restrict__ fcb,
                                             float* __restrict__ out) {
    __shared__ float p[C2_];
    int b = blockIdx.x, c = threadIdx.x;
    float s = 0.0f;
    for (int l = 0; l < L_; ++l)
        s += accl[((size_t)b * L_ + l) * C2_ + c];
    p[c] = s * (1.0f / 65536.0f);     // / (T * L), exact pow2
    __syncthreads();
    if (c < 4) {
        float o = fcb[c];
        #pragma unroll 8
        for (int i = 0; i < C2_; ++i)
            o = fmaf(fcw[c * C2_ + i], p[i], o);
        out[b * 4 + c] = o;
    }
}

extern "C" void kernel_launch(void* const* d_in, const int* in_sizes, int n_in,
                              void* d_out, int out_size, void* d_ws, size_t ws_size,
                              hipStream_t stream) {
    const float* x   = (const float*)d_in[0];
    const float* w1  = (const float*)d_in[1];
    const float* b1  = (const float*)d_in[2];
    const float* w2  = (const float*)d_in[3];
    const float* b2  = (const float*)d_in[4];
    const float* fcw = (const float*)d_in[5];
    const float* fcb = (const float*)d_in[6];
    float* out = (float*)d_out;

    char* ws = (char*)d_ws;
    ushort* s1t  = (ushort*)(ws + WS_S1T);
    ushort* w2h  = (ushort*)(ws + WS_W2HI);
    float*  accl = (float*)(ws + WS_ACCL);

    k0_prep_w2<<<dim3((C2_ * K_ * C1_ + 255) / 256), dim3(256), 0, stream>>>(w2, w2h);
    k1_conv1<<<dim3(L_ / 8, B_), dim3(64, 8), 0, stream>>>(x, w1, b1, s1t);
    k2_conv2_lif<<<dim3(L_ / 2, B_), dim3(256), 0, stream>>>(s1t, w2h, b2, accl);
    k3_fc<<<dim3(B_), dim3(128), 0, stream>>>(accl, fcw, fcb, out);
}